// Round 5
// baseline (155.257 us; speedup 1.0000x reference)
//
#include <hip/hip_runtime.h>

#define D 128
#define RS_STRIDE 64      // floats (256 B) between result slots

typedef __attribute__((ext_vector_type(8))) short bf16x8;
typedef __attribute__((ext_vector_type(8))) unsigned short u16x8;
typedef __attribute__((ext_vector_type(4))) float f32x4;

__device__ __forceinline__ unsigned short f2bf(float f) {
    unsigned u = __float_as_uint(f);
    unsigned r = (u + 0x7fffu + ((u >> 16) & 1u)) >> 16;
    return (unsigned short)r;
}
__device__ __forceinline__ float bf2f(unsigned short h) {
    return __uint_as_float(((unsigned)h) << 16);
}
__device__ __forceinline__ ushort4 pack4(float4 v) {
    ushort4 o; o.x = f2bf(v.x); o.y = f2bf(v.y); o.z = f2bf(v.z); o.w = f2bf(v.w);
    return o;
}

// -------------------------------------------------------------------------
// One fused prep pass: emb fp32->bf16 (if n4>0), W/M fp32->bf16, zero strided
// rs slots, and build row_ptr[N+1] from sorted segment_ids (thread i<E).
__global__ void prep_kernel(const float* __restrict__ emb, const float* __restrict__ W,
                            const float* __restrict__ M, const int* __restrict__ seg,
                            unsigned short* __restrict__ embb, unsigned short* __restrict__ Wb,
                            unsigned short* __restrict__ Mb, float* __restrict__ rs,
                            int* __restrict__ row_ptr, int n4, int E, int N) {
    int i = blockIdx.x * blockDim.x + threadIdx.x;
    if (i < n4) ((ushort4*)embb)[i] = pack4(((const float4*)emb)[i]);
    if (i < 4096)       ((ushort4*)Wb)[i]        = pack4(((const float4*)W)[i]);
    else if (i < 8192)  ((ushort4*)Mb)[i - 4096] = pack4(((const float4*)M)[i - 4096]);
    if (i < D) rs[i * RS_STRIDE] = 0.0f;
    if (i < E) {
        int s = seg[i];
        if (i == 0) {
            for (int n = 0; n <= s; ++n) row_ptr[n] = 0;
        } else {
            int sp = seg[i - 1];
            for (int n = sp + 1; n <= s; ++n) row_ptr[n] = i;
        }
        if (i == E - 1) {
            for (int n = s + 1; n <= N; ++n) row_ptr[n] = E;
        }
    }
}

// -------------------------------------------------------------------------
// Segment-sum of bf16 emb rows -> bf16 aggb. Block = 4 nodes; per node:
// 16 edge streams x 4 lanes/edge; each lane loads 4x16B chunks (c,c+4,c+8,c+12)
// with next-edge id software-prefetched -> ~5 loads in flight per lane.
__global__ void agg_bf_kernel(const int* __restrict__ nbr, const int* __restrict__ row_ptr,
                              const unsigned short* __restrict__ embb,
                              unsigned short* __restrict__ aggb, int N) {
    int n = blockIdx.x * 4 + (threadIdx.x >> 6);
    if (n >= N) return;
    int tt = threadIdx.x & 63;
    int c = tt & 3;       // chunk base (u16x8 index)
    int j = tt >> 2;      // edge stream 0..15

    int lo = row_ptr[n], hi = row_ptr[n + 1];

    float s[4][8];
#pragma unroll
    for (int q = 0; q < 4; ++q)
#pragma unroll
        for (int k = 0; k < 8; ++k) s[q][k] = 0.f;

    int e = lo + j;
    int id = (e < hi) ? nbr[e] : -1;
    while (id >= 0) {
        const u16x8* r = (const u16x8*)(embb + (size_t)id * D);
        int e2 = e + 16;
        int id2 = (e2 < hi) ? nbr[e2] : -1;   // prefetch next id
        u16x8 v0 = r[c], v1 = r[c + 4], v2 = r[c + 8], v3 = r[c + 12];
#pragma unroll
        for (int k = 0; k < 8; ++k) {
            s[0][k] += bf2f((unsigned short)v0[k]);
            s[1][k] += bf2f((unsigned short)v1[k]);
            s[2][k] += bf2f((unsigned short)v2[k]);
            s[3][k] += bf2f((unsigned short)v3[k]);
        }
        e = e2; id = id2;
    }
    // fold 16 streams (xor over lane bits 2..5)
#pragma unroll
    for (int q = 0; q < 4; ++q)
#pragma unroll
        for (int k = 0; k < 8; ++k) {
            float x = s[q][k];
            x += __shfl_xor(x, 4);
            x += __shfl_xor(x, 8);
            x += __shfl_xor(x, 16);
            x += __shfl_xor(x, 32);
            s[q][k] = x;
        }

    if (j == 0) {
        u16x8* o = (u16x8*)(aggb + (size_t)n * D);
#pragma unroll
        for (int q = 0; q < 4; ++q) {
            u16x8 ov;
#pragma unroll
            for (int k = 0; k < 8; ++k) ov[k] = f2bf(s[q][k]);
            o[c + 4 * q] = ov;
        }
    }
}

// Fallback: gather fp32 emb directly (when ws can't hold embb).
__global__ void agg_f32_kernel(const int* __restrict__ nbr, const int* __restrict__ row_ptr,
                               const float* __restrict__ emb,
                               unsigned short* __restrict__ aggb, int N) {
    int n = blockIdx.x * 4 + (threadIdx.x >> 6);
    if (n >= N) return;
    int tt = threadIdx.x & 63;
    int c = tt & 7;
    int j = tt >> 3;

    int lo = row_ptr[n], hi = row_ptr[n + 1];

    float4 s0 = make_float4(0.f, 0.f, 0.f, 0.f);
    float4 s1 = make_float4(0.f, 0.f, 0.f, 0.f);
    float4 s2 = make_float4(0.f, 0.f, 0.f, 0.f);
    float4 s3 = make_float4(0.f, 0.f, 0.f, 0.f);
    for (int e = lo + j; e < hi; e += 8) {
        const float4* r = (const float4*)&emb[(size_t)nbr[e] * D];
        float4 v0 = r[c], v1 = r[c + 8], v2 = r[c + 16], v3 = r[c + 24];
        s0.x += v0.x; s0.y += v0.y; s0.z += v0.z; s0.w += v0.w;
        s1.x += v1.x; s1.y += v1.y; s1.z += v1.z; s1.w += v1.w;
        s2.x += v2.x; s2.y += v2.y; s2.z += v2.z; s2.w += v2.w;
        s3.x += v3.x; s3.y += v3.y; s3.z += v3.z; s3.w += v3.w;
    }
#pragma unroll
    for (int o = 8; o <= 32; o <<= 1) {
        s0.x += __shfl_xor(s0.x, o); s0.y += __shfl_xor(s0.y, o);
        s0.z += __shfl_xor(s0.z, o); s0.w += __shfl_xor(s0.w, o);
        s1.x += __shfl_xor(s1.x, o); s1.y += __shfl_xor(s1.y, o);
        s1.z += __shfl_xor(s1.z, o); s1.w += __shfl_xor(s1.w, o);
        s2.x += __shfl_xor(s2.x, o); s2.y += __shfl_xor(s2.y, o);
        s2.z += __shfl_xor(s2.z, o); s2.w += __shfl_xor(s2.w, o);
        s3.x += __shfl_xor(s3.x, o); s3.y += __shfl_xor(s3.y, o);
        s3.z += __shfl_xor(s3.z, o); s3.w += __shfl_xor(s3.w, o);
    }
    if (j == 0) {
        ushort4* o = (ushort4*)(aggb + (size_t)n * D);
        o[c]      = pack4(s0);
        o[c + 8]  = pack4(s1);
        o[c + 16] = pack4(s2);
        o[c + 24] = pack4(s3);
    }
}

// -------------------------------------------------------------------------
// MFMA matvec + relu + column-sum. Wave job = (dim-tile dt, node stripe);
// each wave handles 2 16-node groups. X-fragments gathered via node_ids.
// A-frag: A[m=lane&15][k=quad*8+j]; B-frag: B[k=quad*8+j][n=lane&15] = W[n][k]
// C/D: col=lane&15 (dim), row=quad*4+reg (node).
template <bool BF>
__global__ __launch_bounds__(256) void matvec_kernel(
    const int* __restrict__ node_ids, const void* __restrict__ embv,
    const unsigned short* __restrict__ aggb,
    const unsigned short* __restrict__ Wb, const unsigned short* __restrict__ Mb,
    float* __restrict__ rs, int N, int ngroups, int nstripes) {
    int t = threadIdx.x;
    int wid = blockIdx.x * 4 + (t >> 6);
    int l = t & 63;
    int quad = l >> 4, col = l & 15;
    int dt = wid & 7;
    int stripe = wid >> 3;

    bf16x8 bw[4], bm[4];
    int wrow = (dt * 16 + col) * D;
#pragma unroll
    for (int ks = 0; ks < 4; ++ks) {
        int off = wrow + ks * 32 + quad * 8;
        bw[ks] = *(const bf16x8*)(Wb + off);
        bm[ks] = *(const bf16x8*)(Mb + off);
    }

    const bf16x8 zero8 = {0, 0, 0, 0, 0, 0, 0, 0};
    float vsum = 0.f;

    for (int grp = stripe; grp < ngroups; grp += nstripes) {
        int node = grp * 16 + col;
        bool valid = node < N;
        int nid = valid ? node_ids[node] : 0;
        const unsigned short* ar = aggb + (size_t)node * D + quad * 8;

        f32x4 acc = {0.f, 0.f, 0.f, 0.f};
#pragma unroll
        for (int ks = 0; ks < 4; ++ks) {
            bf16x8 ax;
            if (BF) {
                const unsigned short* xr =
                    (const unsigned short*)embv + (size_t)nid * D + quad * 8;
                ax = valid ? *(const bf16x8*)(xr + ks * 32) : zero8;
            } else {
                if (valid) {
                    const float4* xf = (const float4*)((const float*)embv +
                                       (size_t)nid * D + quad * 8 + ks * 32);
                    ushort4 p0 = pack4(xf[0]);
                    ushort4 p1 = pack4(xf[1]);
                    ax[0] = (short)p0.x; ax[1] = (short)p0.y;
                    ax[2] = (short)p0.z; ax[3] = (short)p0.w;
                    ax[4] = (short)p1.x; ax[5] = (short)p1.y;
                    ax[6] = (short)p1.z; ax[7] = (short)p1.w;
                } else ax = zero8;
            }
            bf16x8 aa = valid ? *(const bf16x8*)(ar + ks * 32) : zero8;
            acc = __builtin_amdgcn_mfma_f32_16x16x32_bf16(ax, bw[ks], acc, 0, 0, 0);
            acc = __builtin_amdgcn_mfma_f32_16x16x32_bf16(aa, bm[ks], acc, 0, 0, 0);
        }
        vsum += fmaxf(acc[0], 0.f) + fmaxf(acc[1], 0.f)
              + fmaxf(acc[2], 0.f) + fmaxf(acc[3], 0.f);
    }

    vsum += __shfl_xor(vsum, 16);
    vsum += __shfl_xor(vsum, 32);
    if (l < 16) atomicAdd(&rs[(dt * 16 + col) * RS_STRIDE], vsum);
}

// -------------------------------------------------------------------------
__global__ void softmax_kernel(const float* __restrict__ rs, float* __restrict__ out) {
    int t = threadIdx.x;                 // 0..63
    float v0 = rs[t * RS_STRIDE];
    float v1 = rs[(t + 64) * RS_STRIDE];
    float m = fmaxf(v0, v1);
    for (int o = 32; o > 0; o >>= 1) m = fmaxf(m, __shfl_xor(m, o));
    float e0 = expf(v0 - m);
    float e1 = expf(v1 - m);
    float s = e0 + e1;
    for (int o = 32; o > 0; o >>= 1) s += __shfl_xor(s, o);
    float inv = 1.0f / s;
    out[t] = e0 * inv;
    out[t + 64] = e1 * inv;
}

extern "C" void kernel_launch(void* const* d_in, const int* in_sizes, int n_in,
                              void* d_out, int out_size, void* d_ws, size_t ws_size,
                              hipStream_t stream) {
    const int*   node_ids = (const int*)d_in[0];
    const int*   nbr      = (const int*)d_in[1];
    const int*   seg      = (const int*)d_in[2];
    const float* W        = (const float*)d_in[3];
    const float* M        = (const float*)d_in[4];
    const float* emb      = (const float*)d_in[5];
    float* out = (float*)d_out;

    int N = in_sizes[0];
    int E = in_sizes[1];
    long long VD = in_sizes[5];          // V*D elements
    int ngroups  = (N + 15) / 16;
    int nstripes = (ngroups + 1) / 2;    // each wave: exactly 2 groups
    int mv_blocks = 2 * nstripes;        // 8*nstripes waves / 4 waves-per-block

    // ws layout: aggb[N*D] u16 | Wb | Mb | rs fp32 | row_ptr int | embb[V*D] u16
    unsigned short* aggb = (unsigned short*)d_ws;
    unsigned short* Wb   = aggb + (size_t)N * D;
    unsigned short* Mb   = Wb + D * D;
    float* rs            = (float*)(Mb + D * D);
    int* row_ptr         = (int*)(rs + (size_t)D * RS_STRIDE);
    unsigned short* embb = (unsigned short*)(row_ptr + (N + 1));

    size_t need_bf = (size_t)(row_ptr + (N + 1) - (int*)d_ws) * 4 + (size_t)VD * 2;
    bool use_bf = ws_size >= need_bf;
    int n4 = use_bf ? (int)(VD / 4) : 0;
    int prep_n = n4;
    if (prep_n < E) prep_n = E;
    if (prep_n < 8192) prep_n = 8192;

    prep_kernel<<<(prep_n + 255) / 256, 256, 0, stream>>>(emb, W, M, seg, embb, Wb, Mb,
                                                          rs, row_ptr, n4, E, N);
    if (use_bf) {
        agg_bf_kernel<<<(N + 3) / 4, 256, 0, stream>>>(nbr, row_ptr, embb, aggb, N);
        matvec_kernel<true><<<mv_blocks, 256, 0, stream>>>(node_ids, embb, aggb, Wb, Mb,
                                                           rs, N, ngroups, nstripes);
    } else {
        agg_f32_kernel<<<(N + 3) / 4, 256, 0, stream>>>(nbr, row_ptr, emb, aggb, N);
        matvec_kernel<false><<<mv_blocks, 256, 0, stream>>>(node_ids, emb, aggb, Wb, Mb,
                                                            rs, N, ngroups, nstripes);
    }
    softmax_kernel<<<1, 64, 0, stream>>>(rs, out);
}